// Round 15
// baseline (531.876 us; speedup 1.0000x reference)
//
#include <hip/hip_runtime.h>
#include <math.h>

#define TT 512
#define BB 512
#define CC 32
#define CIN 33
#define HH 128
#define EPSF 1e-12f
#define CH 16              // timesteps per x-chunk staged in LDS
#define NCH (TT / CH)
#define RB 2               // batch rows per block
#define HSP 160            // hs row stride (halves): 320 B == 16 banks -> rows disjoint
#define XSP 96             // xs row stride (halves): 192 B == 16 banks
#define CNT_IDX 515        // ws poison 0xAAAAAAAA is the deterministic counter base

typedef _Float16 half8 __attribute__((ext_vector_type(8)));
typedef _Float16 half4v __attribute__((ext_vector_type(4)));
typedef _Float16 half2v __attribute__((ext_vector_type(2)));
typedef float f32x4 __attribute__((ext_vector_type(4)));

#define MFMA16H(a, b, c) __builtin_amdgcn_mfma_f32_16x16x32_f16(a, b, c, 0, 0, 0)

__device__ __forceinline__ float fsig(float x) {
    return __builtin_amdgcn_rcpf(1.f + __expf(-x));
}
__device__ __forceinline__ float ftanh(float x) {
    return 1.f - 2.f * __builtin_amdgcn_rcpf(1.f + __expf(2.f * x));
}
// full-wave (64) sum via DPP; result valid on lane 63 ONLY.
__device__ __forceinline__ float wave_sum_dpp(float x) {
    x += __int_as_float(__builtin_amdgcn_update_dpp(0, __float_as_int(x), 0x111, 0xf, 0xf, true));
    x += __int_as_float(__builtin_amdgcn_update_dpp(0, __float_as_int(x), 0x112, 0xf, 0xf, true));
    x += __int_as_float(__builtin_amdgcn_update_dpp(0, __float_as_int(x), 0x114, 0xf, 0xf, true));
    x += __int_as_float(__builtin_amdgcn_update_dpp(0, __float_as_int(x), 0x118, 0xf, 0xf, true));
    x += __int_as_float(__builtin_amdgcn_update_dpp(0, __float_as_int(x), 0x142, 0xa, 0xf, true));
    x += __int_as_float(__builtin_amdgcn_update_dpp(0, __float_as_int(x), 0x143, 0xc, 0xf, true));
    return x;
}
// sum within each 16-lane row; result valid on lanes 15/31/47/63.
__device__ __forceinline__ float row_sum_dpp(float x) {
    x += __int_as_float(__builtin_amdgcn_update_dpp(0, __float_as_int(x), 0x111, 0xf, 0xf, true));
    x += __int_as_float(__builtin_amdgcn_update_dpp(0, __float_as_int(x), 0x112, 0xf, 0xf, true));
    x += __int_as_float(__builtin_amdgcn_update_dpp(0, __float_as_int(x), 0x114, 0xf, 0xf, true));
    x += __int_as_float(__builtin_amdgcn_update_dpp(0, __float_as_int(x), 0x118, 0xf, 0xf, true));
    return x;
}

// ---------------------------------------------------------------------------
// Fused kernel: 256 blocks x 512 threads, waves_per_eu(2,2).
// Phase A: block b computes std feature for t=2b,2b+1 -> ws (agent atomics).
// Phase B: block-local redundant sigmas (no cross-block traffic).
// Phase C: weight conversion. Phase D: device-scope spin barrier
// (base = 0xAA poison, graceful exit on any other init; 2-blocks/CU capacity
// guarantees all 256 blocks co-resident -> no deadlock).
// Phase E: R11 lstm (known-good 394-398 us, 0 bank conflicts).
// ---------------------------------------------------------------------------
__global__ __attribute__((amdgpu_flat_work_group_size(512, 512), amdgpu_waves_per_eu(2, 2)))
void critic_fused(
    const float* __restrict__ x,
    const float* __restrict__ w_ih, const float* __restrict__ u_ih,
    const float* __restrict__ w_hh, const float* __restrict__ u_hh,
    const float* __restrict__ b_ih, const float* __restrict__ b_hh,
    const float* __restrict__ attn_w, const float* __restrict__ attn_b,
    const float* __restrict__ fc_w, const float* __restrict__ u_fc,
    const float* __restrict__ fc_b,
    float* __restrict__ ws,
    float* __restrict__ out)
{
    const int tid = threadIdx.x;
    const int w   = tid >> 6;          // wave 0..7
    const int l   = tid & 63;          // lane
    const int m   = l & 15;            // A-row / B-col index
    const int q   = l >> 4;            // quad 0..3
    const int r   = q & 1;             // this lane's batch row (duplicated rows)
    const int b0  = blockIdx.x * RB;
    const int jcol = 16 * w + m;       // this lane's h column

    unsigned int* cntp = (unsigned int*)ws + CNT_IDX;

    // ---- LDS ----
    __shared__ float4 sS[64][8];                            // std scratch
    __shared__ float4 sQ[64][8];
    __shared__ float red[512];                              // sigma scratch
    __shared__ float vv[128];
    __shared__ float sigS[3];                               // sig_ih, sig_hh, sig_fc
    __shared__ __align__(16) _Float16 hs[2][RB][HSP];       // h planes
    __shared__ __align__(16) _Float16 xs[2][CH][RB][XSP];   // x chunks
    __shared__ float ss[2][CH];
    __shared__ __align__(8) float bcast[2][RB];             // beta per row
    __shared__ float Sf[RB];
    __shared__ float part[8][RB];                           // FC partials

    // ================= Phase A: std for t = 2*bid, 2*bid+1 =================
    {
        const int c4 = tid & 7;       // c = c4*4 .. c4*4+3
        const int bs = tid >> 3;      // 64 groups of 8 batch rows
#pragma unroll
        for (int tt = 0; tt < 2; ++tt) {
            const int t = 2 * blockIdx.x + tt;
            float4 S = make_float4(0.f, 0.f, 0.f, 0.f);
            float4 Q = make_float4(0.f, 0.f, 0.f, 0.f);
#pragma unroll
            for (int i = 0; i < 8; ++i) {
                const int b = bs * 8 + i;
                float4 v = *reinterpret_cast<const float4*>(
                    x + ((size_t)b * TT + t) * CC + c4 * 4);
                S.x += v.x; S.y += v.y; S.z += v.z; S.w += v.w;
                Q.x = fmaf(v.x, v.x, Q.x); Q.y = fmaf(v.y, v.y, Q.y);
                Q.z = fmaf(v.z, v.z, Q.z); Q.w = fmaf(v.w, v.w, Q.w);
            }
            sS[bs][c4] = S; sQ[bs][c4] = Q;
            __syncthreads();
            for (int s = 32; s >= 1; s >>= 1) {
                if (bs < s) {
                    float4 a = sS[bs][c4], b4 = sS[bs + s][c4];
                    float4 e = sQ[bs][c4], f4 = sQ[bs + s][c4];
                    sS[bs][c4] = make_float4(a.x + b4.x, a.y + b4.y, a.z + b4.z, a.w + b4.w);
                    sQ[bs][c4] = make_float4(e.x + f4.x, e.y + f4.y, e.z + f4.z, e.w + f4.w);
                }
                __syncthreads();
            }
            if (tid < 8) {
                float4 S4 = sS[0][tid], Q4 = sQ[0][tid];
                float st = 0.f;
#pragma unroll
                for (int i = 0; i < 4; ++i) {
                    float s1 = (i == 0) ? S4.x : (i == 1) ? S4.y : (i == 2) ? S4.z : S4.w;
                    float q1 = (i == 0) ? Q4.x : (i == 1) ? Q4.y : (i == 2) ? Q4.z : Q4.w;
                    float mean = s1 / 512.0f;
                    float var  = (q1 - 512.0f * mean * mean) / 511.0f;
                    st += sqrtf(fmaxf(var, 0.f));
                }
                sS[1][tid].x = st;
            }
            __syncthreads();
            if (tid == 0) {
                float mm = 0.f;
                for (int i = 0; i < 8; ++i) mm += sS[1][i].x;
                __hip_atomic_store(&ws[t], mm / 32.0f, __ATOMIC_RELEASE,
                                   __HIP_MEMORY_SCOPE_AGENT);
            }
            __syncthreads();
        }
        __threadfence();
        if (tid == 0) atomicAdd(cntp, 1u);   // arrive (device scope)
    }

    // ================= Phase B: block-local sigmas =================
    {
        const int wv_ = w;
        {   // sigma_hh
            const int c = tid & 127, qq = tid >> 7;
            float p0 = 0.f;
            for (int g = qq * 128; g < qq * 128 + 128; ++g)
                p0 = fmaf(w_hh[g * HH + c], u_hh[g], p0);
            red[tid] = p0;
            __syncthreads();
            if (tid < 128) vv[tid] = red[tid] + red[tid + 128] + red[tid + 256] + red[tid + 384];
            __syncthreads();
            red[tid] = (tid < 128) ? vv[tid] * vv[tid] : 0.f;
            __syncthreads();
            for (int s = 64; s >= 1; s >>= 1) { if (tid < s) red[tid] += red[tid + s]; __syncthreads(); }
            const float nv = sqrtf(red[0]);
            __syncthreads();
            if (tid < 128) vv[tid] = vv[tid] / (nv + EPSF);
            __syncthreads();
            float sq = 0.f;
            for (int gi = 0; gi < 64; ++gi) {
                const int g = wv_ * 64 + gi;
                float2 wl = *reinterpret_cast<const float2*>(&w_hh[(size_t)g * HH + 2 * l]);
                float2 vl = *reinterpret_cast<const float2*>(&vv[2 * l]);
                float p  = fmaf(wl.x, vl.x, wl.y * vl.y);
                float tot = wave_sum_dpp(p);
                sq = fmaf(tot, tot, sq);
            }
            if (l == 63) red[wv_] = sq;
            __syncthreads();
            if (tid == 0) {
                float ns2 = 0.f;
                for (int i = 0; i < 8; ++i) ns2 += red[i];
                sigS[1] = ns2 / (sqrtf(ns2) + EPSF);
            }
            __syncthreads();
        }
        {   // sigma_ih : u-projection split across 8 waves
            if (l < CIN) {
                float p0 = 0.f;
                for (int gi = 0; gi < 64; ++gi) {
                    const int g = wv_ * 64 + gi;
                    p0 = fmaf(w_ih[(size_t)g * CIN + l], u_ih[g], p0);
                }
                red[wv_ * 64 + l] = p0;
            }
            __syncthreads();
            if (tid < CIN) {
                float v = 0.f;
#pragma unroll
                for (int i = 0; i < 8; ++i) v += red[i * 64 + tid];
                vv[tid] = v;
            }
            __syncthreads();
            if (tid == 0) {
                float n2 = 0.f;
                for (int i = 0; i < CIN; ++i) n2 += vv[i] * vv[i];
                red[400] = sqrtf(n2);
            }
            __syncthreads();
            const float nv = red[400];
            if (tid < CIN) vv[tid] = vv[tid] / (nv + EPSF);
            __syncthreads();
            float vl = (l < CIN) ? vv[l] : 0.f;
            float sq = 0.f;
            for (int gi = 0; gi < 64; ++gi) {
                const int g = wv_ * 64 + gi;
                float p = (l < CIN) ? w_ih[(size_t)g * CIN + l] * vl : 0.f;
                float tot = wave_sum_dpp(p);
                sq = fmaf(tot, tot, sq);
            }
            if (l == 63) red[wv_] = sq;
            __syncthreads();
            if (tid == 0) {
                float ns2 = 0.f;
                for (int i = 0; i < 8; ++i) ns2 += red[i];
                sigS[0] = ns2 / (sqrtf(ns2) + EPSF);
            }
            __syncthreads();
        }
        {   // sigma_fc
            red[tid] = (tid < 128) ? fc_w[tid] * fc_w[tid] : 0.f;
            __syncthreads();
            for (int s = 64; s >= 1; s >>= 1) { if (tid < s) red[tid] += red[tid + s]; __syncthreads(); }
            if (tid == 0) {
                float nw2 = red[0];
                float u0  = u_fc[0];
                float nv  = fabsf(u0) * sqrtf(nw2);
                float wv  = u0 * nw2 / (nv + EPSF);
                sigS[2]   = wv * wv / (fabsf(wv) + EPSF);
            }
            __syncthreads();
        }
    }
    const float rih = 1.f / sigS[0];
    const float rhh = 1.f / sigS[1];
    const float rfc = 1.f / sigS[2];
    const float attb = attn_b[0];

    // ================= Phase C: weight conversion (R11) =================
    half8 Bf[4][5];
    float biasg[4], w32g[4];
#pragma unroll
    for (int p = 0; p < 4; ++p) {
        const int g = 16 * w + 128 * p + m;
#pragma unroll
        for (int kt = 0; kt < 4; ++kt) {
            const float* src = w_hh + (size_t)g * HH + kt * 32 + q * 8;
#pragma unroll
            for (int i = 0; i < 8; ++i) Bf[p][kt][i] = (_Float16)(src[i] * rhh);
        }
        {
            const float* src = w_ih + (size_t)g * CIN + q * 8;
#pragma unroll
            for (int i = 0; i < 8; ++i) Bf[p][4][i] = (_Float16)(src[i] * rih);
        }
        w32g[p]  = w_ih[(size_t)g * CIN + 32] * rih;
        biasg[p] = b_ih[g] + b_hh[g];
    }
    f32x4 zero4 = (f32x4){0.f, 0.f, 0.f, 0.f};
#pragma unroll
    for (int p = 0; p < 4; ++p) {
#pragma unroll
        for (int kt = 0; kt < 5; ++kt) asm volatile("" : "+v"(Bf[p][kt]));
        asm volatile("" : "+v"(biasg[p]), "+v"(w32g[p]));
    }
    asm volatile("" : "+v"(zero4));
    const float fcwj = fc_w[jcol] * rfc;
    const float aw0 = attn_w[2 * l];
    const float aw1 = attn_w[2 * l + 1];

    // ================= Phase D: device-scope spin barrier =================
    if (tid == 0) {
        const unsigned int base = 0xAAAAAAAAu;   // documented d_ws poison
        for (int it = 0; it < 20000000; ++it) {
            unsigned int v = __hip_atomic_load(cntp, __ATOMIC_ACQUIRE,
                                               __HIP_MEMORY_SCOPE_AGENT);
            if (v - base >= 256u) break;         // any other init -> exits at once
        }
    }
    __syncthreads();

    // ================= Phase E: lstm main (R11 structure) =================
    // zero h_{-1} planes (both buffers)
    for (int i = tid; i < 2 * RB * HSP; i += 512) (&hs[0][0][0])[i] = (_Float16)0.f;
    // stage chunk 0 + ss[0]
    if (tid < 256) {
        const int c4 = tid & 7, rr = (tid >> 3) & 1, k = tid >> 4;
        float4 xv = *reinterpret_cast<const float4*>(x + ((size_t)(b0 + rr) * TT + k) * CC + c4 * 4);
        half4v hv = {(_Float16)xv.x, (_Float16)xv.y, (_Float16)xv.z, (_Float16)xv.w};
        *(half4v*)&xs[0][k][rr][c4 * 4] = hv;
    }
    if (tid < CH)
        ss[0][tid] = __hip_atomic_load(&ws[tid], __ATOMIC_RELAXED, __HIP_MEMORY_SCOPE_AGENT);

    float c_st = 0.f, P = 0.f, hprev = 0.f, hpp = 0.f;  // per-lane, row r
    float Sreg = 0.f;                                    // lane 63 of waves 0,1
    __syncthreads();

    for (int tc = 0; tc < NCH; ++tc) {
        const int cb = tc & 1;

        // stage next chunk
        if (tc + 1 < NCH) {
            const int nb  = (tc + 1) & 1;
            const int t0n = (tc + 1) * CH;
            if (tid < 256) {
                const int c4 = tid & 7, rr = (tid >> 3) & 1, k = tid >> 4;
                float4 xv = *reinterpret_cast<const float4*>(
                    x + ((size_t)(b0 + rr) * TT + (t0n + k)) * CC + c4 * 4);
                half4v hv = {(_Float16)xv.x, (_Float16)xv.y, (_Float16)xv.z, (_Float16)xv.w};
                *(half4v*)&xs[nb][k][rr][c4 * 4] = hv;
            }
            if (tid < CH)
                ss[nb][tid] = __hip_atomic_load(&ws[t0n + tid], __ATOMIC_RELAXED,
                                                __HIP_MEMORY_SCOPE_AGENT);
        }

        for (int k = 0; k < CH; ++k) {
            const int t  = tc * CH + k;
            const int hb = (t + 1) & 1;    // buffer holding h_{t-1}

            // ---- A-frags: all lanes read duplicated rows (m&1) ----
            half8 ah0 = *(const half8*)&hs[hb][m & 1][0 * 32 + q * 8];
            half8 ah1 = *(const half8*)&hs[hb][m & 1][1 * 32 + q * 8];
            half8 ah2 = *(const half8*)&hs[hb][m & 1][2 * 32 + q * 8];
            half8 ah3 = *(const half8*)&hs[hb][m & 1][3 * 32 + q * 8];
            half8 ah4 = *(const half8*)&xs[cb][k][m & 1][q * 8];
            const float s_t = ss[cb][k];

            // logit source read issued early (h_{t-1}, buffer hb)
            float dotp = 0.f;
            if (t > 0 && w < RB) {
                half2v hh = *(const half2v*)&hs[hb][w][2 * l];
                dotp = fmaf(aw0, (float)hh[0], aw1 * (float)hh[1]);
            }

            // ---- P update for h_{t-2} (beta written at step t-1) ----
            if (t >= 2) P = fmaf(bcast[(t - 1) & 1][r], hpp, P);

            // ---- gates: 20 MFMA from zero C, 4 interleaved chains ----
            f32x4 acc0 = MFMA16H(ah0, Bf[0][0], zero4);
            f32x4 acc1 = MFMA16H(ah0, Bf[1][0], zero4);
            f32x4 acc2 = MFMA16H(ah0, Bf[2][0], zero4);
            f32x4 acc3 = MFMA16H(ah0, Bf[3][0], zero4);
            acc0 = MFMA16H(ah1, Bf[0][1], acc0);
            acc1 = MFMA16H(ah1, Bf[1][1], acc1);
            acc2 = MFMA16H(ah1, Bf[2][1], acc2);
            acc3 = MFMA16H(ah1, Bf[3][1], acc3);
            acc0 = MFMA16H(ah2, Bf[0][2], acc0);
            acc1 = MFMA16H(ah2, Bf[1][2], acc1);
            acc2 = MFMA16H(ah2, Bf[2][2], acc2);
            acc3 = MFMA16H(ah2, Bf[3][2], acc3);
            acc0 = MFMA16H(ah3, Bf[0][3], acc0);
            acc1 = MFMA16H(ah3, Bf[1][3], acc1);
            acc2 = MFMA16H(ah3, Bf[2][3], acc2);
            acc3 = MFMA16H(ah3, Bf[3][3], acc3);
            acc0 = MFMA16H(ah4, Bf[0][4], acc0);
            acc1 = MFMA16H(ah4, Bf[1][4], acc1);
            acc2 = MFMA16H(ah4, Bf[2][4], acc2);
            acc3 = MFMA16H(ah4, Bf[3][4], acc3);

            // ---- logit reduction (DPP) overlaps MFMA latency ----
            if (t > 0 && w < RB) {
                float tot = wave_sum_dpp(dotp);
                if (l == 63) {
                    float beta = __expf(tot + attb);
                    Sreg += beta;
                    bcast[t & 1][w] = beta;
                }
            }

            // ---- activations: full wave, reg r = this lane's row ----
            {
                float g0 = acc0[r] + fmaf(w32g[0], s_t, biasg[0]);
                float g1 = acc1[r] + fmaf(w32g[1], s_t, biasg[1]);
                float g2 = acc2[r] + fmaf(w32g[2], s_t, biasg[2]);
                float g3 = acc3[r] + fmaf(w32g[3], s_t, biasg[3]);
                float ig = fsig(g0);
                float fg = fsig(g1);
                float gg = ftanh(g2);
                float og = fsig(g3);
                c_st = fmaf(fg, c_st, ig * gg);
                float hv = og * ftanh(c_st);
                hpp   = hprev;
                hprev = hv;
                if (q < 2) hs[t & 1][r][jcol] = (_Float16)hv;
            }

            __syncthreads();   // single barrier per step
        }
    }

    // ---- epilogue ----
    P = fmaf(bcast[1][r], hpp, P);
    if (w < RB) {
        half2v hh = *(const half2v*)&hs[1][w][2 * l];
        float dotp = fmaf(aw0, (float)hh[0], aw1 * (float)hh[1]);
        float tot = wave_sum_dpp(dotp);
        if (l == 63) {
            float beta = __expf(tot + attb);
            Sreg += beta;
            bcast[0][w] = beta;
            Sf[w] = Sreg;
        }
    }
    __syncthreads();
    {
        float Pv = fmaf(bcast[0][r], hprev, P);
        float v  = Pv * __builtin_amdgcn_rcpf(Sf[r]) * fcwj;
        float rs = row_sum_dpp(v);
        if (l == 15) part[w][0] = rs;       // row 0 sum (q=0)
        if (l == 31) part[w][1] = rs;       // row 1 sum (q=1)
    }
    __syncthreads();
    if (tid < RB) {
        float a = 0.f;
#pragma unroll
        for (int i = 0; i < 8; ++i) a += part[i][tid];
        out[b0 + tid] = a + fc_b[0];
    }
}

// ---------------------------------------------------------------------------
extern "C" void kernel_launch(void* const* d_in, const int* in_sizes, int n_in,
                              void* d_out, int out_size, void* d_ws, size_t ws_size,
                              hipStream_t stream) {
    const float* x      = (const float*)d_in[0];
    const float* w_ih   = (const float*)d_in[1];
    const float* u_ih   = (const float*)d_in[2];
    const float* w_hh   = (const float*)d_in[3];
    const float* u_hh   = (const float*)d_in[4];
    const float* b_ih   = (const float*)d_in[5];
    const float* b_hh   = (const float*)d_in[6];
    const float* attn_w = (const float*)d_in[7];
    const float* attn_b = (const float*)d_in[8];
    const float* fc_w   = (const float*)d_in[9];
    const float* u_fc   = (const float*)d_in[10];
    const float* fc_b   = (const float*)d_in[11];
    float* ws  = (float*)d_ws;
    float* out = (float*)d_out;

    critic_fused<<<BB / RB, 512, 0, stream>>>(x, w_ih, u_ih, w_hh, u_hh, b_ih, b_hh,
                                              attn_w, attn_b, fc_w, u_fc, fc_b, ws, out);
}

// Round 16
// 503.326 us; speedup vs baseline: 1.0567x; 1.0567x over previous
//
#include <hip/hip_runtime.h>
#include <math.h>

#define TT 512
#define BB 512
#define CC 32
#define CIN 33
#define HH 128
#define EPSF 1e-12f
#define CH 16              // timesteps per x-chunk staged in LDS
#define NCH (TT / CH)
#define RB 2               // batch rows per block
#define HSP 160            // hs row stride (halves): 320 B == 16 banks -> rows disjoint
#define XSP 96             // xs row stride (halves): 192 B == 16 banks

typedef _Float16 half8 __attribute__((ext_vector_type(8)));
typedef _Float16 half4v __attribute__((ext_vector_type(4)));
typedef _Float16 half2v __attribute__((ext_vector_type(2)));
typedef float f32x4 __attribute__((ext_vector_type(4)));

#define MFMA16H(a, b, c) __builtin_amdgcn_mfma_f32_16x16x32_f16(a, b, c, 0, 0, 0)

__device__ __forceinline__ float fsig(float x) {
    return __builtin_amdgcn_rcpf(1.f + __expf(-x));
}
__device__ __forceinline__ float ftanh(float x) {
    return 1.f - 2.f * __builtin_amdgcn_rcpf(1.f + __expf(2.f * x));
}
// full-wave (64) sum via DPP; result valid on lane 63 ONLY.
__device__ __forceinline__ float wave_sum_dpp(float x) {
    x += __int_as_float(__builtin_amdgcn_update_dpp(0, __float_as_int(x), 0x111, 0xf, 0xf, true));
    x += __int_as_float(__builtin_amdgcn_update_dpp(0, __float_as_int(x), 0x112, 0xf, 0xf, true));
    x += __int_as_float(__builtin_amdgcn_update_dpp(0, __float_as_int(x), 0x114, 0xf, 0xf, true));
    x += __int_as_float(__builtin_amdgcn_update_dpp(0, __float_as_int(x), 0x118, 0xf, 0xf, true));
    x += __int_as_float(__builtin_amdgcn_update_dpp(0, __float_as_int(x), 0x142, 0xa, 0xf, true));
    x += __int_as_float(__builtin_amdgcn_update_dpp(0, __float_as_int(x), 0x143, 0xc, 0xf, true));
    return x;
}
// sum within each 16-lane row; result valid on lanes 15/31/47/63.
__device__ __forceinline__ float row_sum_dpp(float x) {
    x += __int_as_float(__builtin_amdgcn_update_dpp(0, __float_as_int(x), 0x111, 0xf, 0xf, true));
    x += __int_as_float(__builtin_amdgcn_update_dpp(0, __float_as_int(x), 0x112, 0xf, 0xf, true));
    x += __int_as_float(__builtin_amdgcn_update_dpp(0, __float_as_int(x), 0x114, 0xf, 0xf, true));
    x += __int_as_float(__builtin_amdgcn_update_dpp(0, __float_as_int(x), 0x118, 0xf, 0xf, true));
    return x;
}
// spin-load s[t]: ws is 0xAA-poisoned each launch (negative float sentinel);
// real s[t] >= 0, so bit pattern 0xAAAAAAAA is unambiguous. Bounded spin.
__device__ __forceinline__ float load_s(const float* p) {
    float v = __hip_atomic_load(p, __ATOMIC_ACQUIRE, __HIP_MEMORY_SCOPE_AGENT);
    for (int it = 0; it < 100000000 && __float_as_uint(v) == 0xAAAAAAAAu; ++it)
        v = __hip_atomic_load(p, __ATOMIC_ACQUIRE, __HIP_MEMORY_SCOPE_AGENT);
    return v;
}

// ---------------------------------------------------------------------------
// Fused kernel, NO global barrier. 256 blocks x 512 threads, waves_per_eu(2,2).
// Phase A: block b computes std feature for t=2b,2b+1 -> ws (release stores).
// Phase B: block-local redundant sigmas. Phase C: weight conversion.
// Phase E: R11 lstm; consumers of ws[t] use per-value sentinel spins (only
// possible in the first chunk; all blocks finish phase A at ~the same time).
// Deadlock-free: every block publishes before it ever waits; 256 blocks are
// co-resident at 1 block/CU.
// ---------------------------------------------------------------------------
__global__ __attribute__((amdgpu_flat_work_group_size(512, 512), amdgpu_waves_per_eu(2, 2)))
void critic_fused(
    const float* __restrict__ x,
    const float* __restrict__ w_ih, const float* __restrict__ u_ih,
    const float* __restrict__ w_hh, const float* __restrict__ u_hh,
    const float* __restrict__ b_ih, const float* __restrict__ b_hh,
    const float* __restrict__ attn_w, const float* __restrict__ attn_b,
    const float* __restrict__ fc_w, const float* __restrict__ u_fc,
    const float* __restrict__ fc_b,
    float* __restrict__ ws,
    float* __restrict__ out)
{
    const int tid = threadIdx.x;
    const int w   = tid >> 6;          // wave 0..7
    const int l   = tid & 63;          // lane
    const int m   = l & 15;            // A-row / B-col index
    const int q   = l >> 4;            // quad 0..3
    const int r   = q & 1;             // this lane's batch row (duplicated rows)
    const int b0  = blockIdx.x * RB;
    const int jcol = 16 * w + m;       // this lane's h column

    // ---- LDS ----
    __shared__ float4 sS[64][8];                            // std scratch
    __shared__ float4 sQ[64][8];
    __shared__ float red[512];                              // sigma scratch
    __shared__ float vv[128];
    __shared__ float sigS[3];                               // sig_ih, sig_hh, sig_fc
    __shared__ __align__(16) _Float16 hs[2][RB][HSP];       // h planes
    __shared__ __align__(16) _Float16 xs[2][CH][RB][XSP];   // x chunks
    __shared__ float ss[2][CH];
    __shared__ __align__(8) float bcast[2][RB];             // beta per row
    __shared__ float Sf[RB];
    __shared__ float part[8][RB];                           // FC partials

    // ================= Phase A: std for t = 2*bid, 2*bid+1 =================
    {
        const int c4 = tid & 7;       // c = c4*4 .. c4*4+3
        const int bs = tid >> 3;      // 64 groups of 8 batch rows
#pragma unroll
        for (int tt = 0; tt < 2; ++tt) {
            const int t = 2 * blockIdx.x + tt;
            float4 S = make_float4(0.f, 0.f, 0.f, 0.f);
            float4 Q = make_float4(0.f, 0.f, 0.f, 0.f);
#pragma unroll
            for (int i = 0; i < 8; ++i) {
                const int b = bs * 8 + i;
                float4 v = *reinterpret_cast<const float4*>(
                    x + ((size_t)b * TT + t) * CC + c4 * 4);
                S.x += v.x; S.y += v.y; S.z += v.z; S.w += v.w;
                Q.x = fmaf(v.x, v.x, Q.x); Q.y = fmaf(v.y, v.y, Q.y);
                Q.z = fmaf(v.z, v.z, Q.z); Q.w = fmaf(v.w, v.w, Q.w);
            }
            sS[bs][c4] = S; sQ[bs][c4] = Q;
            __syncthreads();
            for (int s = 32; s >= 1; s >>= 1) {
                if (bs < s) {
                    float4 a = sS[bs][c4], b4 = sS[bs + s][c4];
                    float4 e = sQ[bs][c4], f4 = sQ[bs + s][c4];
                    sS[bs][c4] = make_float4(a.x + b4.x, a.y + b4.y, a.z + b4.z, a.w + b4.w);
                    sQ[bs][c4] = make_float4(e.x + f4.x, e.y + f4.y, e.z + f4.z, e.w + f4.w);
                }
                __syncthreads();
            }
            if (tid < 8) {
                float4 S4 = sS[0][tid], Q4 = sQ[0][tid];
                float st = 0.f;
#pragma unroll
                for (int i = 0; i < 4; ++i) {
                    float s1 = (i == 0) ? S4.x : (i == 1) ? S4.y : (i == 2) ? S4.z : S4.w;
                    float q1 = (i == 0) ? Q4.x : (i == 1) ? Q4.y : (i == 2) ? Q4.z : Q4.w;
                    float mean = s1 / 512.0f;
                    float var  = (q1 - 512.0f * mean * mean) / 511.0f;
                    st += sqrtf(fmaxf(var, 0.f));
                }
                sS[1][tid].x = st;
            }
            __syncthreads();
            if (tid == 0) {
                float mm = 0.f;
                for (int i = 0; i < 8; ++i) mm += sS[1][i].x;
                __hip_atomic_store(&ws[t], mm / 32.0f, __ATOMIC_RELEASE,
                                   __HIP_MEMORY_SCOPE_AGENT);
            }
            __syncthreads();
        }
    }

    // ================= Phase B: block-local sigmas =================
    {
        const int wv_ = w;
        {   // sigma_hh
            const int c = tid & 127, qq = tid >> 7;
            float p0 = 0.f;
            for (int g = qq * 128; g < qq * 128 + 128; ++g)
                p0 = fmaf(w_hh[g * HH + c], u_hh[g], p0);
            red[tid] = p0;
            __syncthreads();
            if (tid < 128) vv[tid] = red[tid] + red[tid + 128] + red[tid + 256] + red[tid + 384];
            __syncthreads();
            red[tid] = (tid < 128) ? vv[tid] * vv[tid] : 0.f;
            __syncthreads();
            for (int s = 64; s >= 1; s >>= 1) { if (tid < s) red[tid] += red[tid + s]; __syncthreads(); }
            const float nv = sqrtf(red[0]);
            __syncthreads();
            if (tid < 128) vv[tid] = vv[tid] / (nv + EPSF);
            __syncthreads();
            float sq = 0.f;
            for (int gi = 0; gi < 64; ++gi) {
                const int g = wv_ * 64 + gi;
                float2 wl = *reinterpret_cast<const float2*>(&w_hh[(size_t)g * HH + 2 * l]);
                float2 vl = *reinterpret_cast<const float2*>(&vv[2 * l]);
                float p  = fmaf(wl.x, vl.x, wl.y * vl.y);
                float tot = wave_sum_dpp(p);
                sq = fmaf(tot, tot, sq);
            }
            if (l == 63) red[wv_] = sq;
            __syncthreads();
            if (tid == 0) {
                float ns2 = 0.f;
                for (int i = 0; i < 8; ++i) ns2 += red[i];
                sigS[1] = ns2 / (sqrtf(ns2) + EPSF);
            }
            __syncthreads();
        }
        {   // sigma_ih : u-projection split across 8 waves
            if (l < CIN) {
                float p0 = 0.f;
                for (int gi = 0; gi < 64; ++gi) {
                    const int g = wv_ * 64 + gi;
                    p0 = fmaf(w_ih[(size_t)g * CIN + l], u_ih[g], p0);
                }
                red[wv_ * 64 + l] = p0;
            }
            __syncthreads();
            if (tid < CIN) {
                float v = 0.f;
#pragma unroll
                for (int i = 0; i < 8; ++i) v += red[i * 64 + tid];
                vv[tid] = v;
            }
            __syncthreads();
            if (tid == 0) {
                float n2 = 0.f;
                for (int i = 0; i < CIN; ++i) n2 += vv[i] * vv[i];
                red[400] = sqrtf(n2);
            }
            __syncthreads();
            const float nv = red[400];
            if (tid < CIN) vv[tid] = vv[tid] / (nv + EPSF);
            __syncthreads();
            float vl = (l < CIN) ? vv[l] : 0.f;
            float sq = 0.f;
            for (int gi = 0; gi < 64; ++gi) {
                const int g = wv_ * 64 + gi;
                float p = (l < CIN) ? w_ih[(size_t)g * CIN + l] * vl : 0.f;
                float tot = wave_sum_dpp(p);
                sq = fmaf(tot, tot, sq);
            }
            if (l == 63) red[wv_] = sq;
            __syncthreads();
            if (tid == 0) {
                float ns2 = 0.f;
                for (int i = 0; i < 8; ++i) ns2 += red[i];
                sigS[0] = ns2 / (sqrtf(ns2) + EPSF);
            }
            __syncthreads();
        }
        {   // sigma_fc
            red[tid] = (tid < 128) ? fc_w[tid] * fc_w[tid] : 0.f;
            __syncthreads();
            for (int s = 64; s >= 1; s >>= 1) { if (tid < s) red[tid] += red[tid + s]; __syncthreads(); }
            if (tid == 0) {
                float nw2 = red[0];
                float u0  = u_fc[0];
                float nv  = fabsf(u0) * sqrtf(nw2);
                float wv  = u0 * nw2 / (nv + EPSF);
                sigS[2]   = wv * wv / (fabsf(wv) + EPSF);
            }
            __syncthreads();
        }
    }
    const float rih = 1.f / sigS[0];
    const float rhh = 1.f / sigS[1];
    const float rfc = 1.f / sigS[2];
    const float attb = attn_b[0];

    // ================= Phase C: weight conversion (R11) =================
    half8 Bf[4][5];
    float biasg[4], w32g[4];
#pragma unroll
    for (int p = 0; p < 4; ++p) {
        const int g = 16 * w + 128 * p + m;
#pragma unroll
        for (int kt = 0; kt < 4; ++kt) {
            const float* src = w_hh + (size_t)g * HH + kt * 32 + q * 8;
#pragma unroll
            for (int i = 0; i < 8; ++i) Bf[p][kt][i] = (_Float16)(src[i] * rhh);
        }
        {
            const float* src = w_ih + (size_t)g * CIN + q * 8;
#pragma unroll
            for (int i = 0; i < 8; ++i) Bf[p][4][i] = (_Float16)(src[i] * rih);
        }
        w32g[p]  = w_ih[(size_t)g * CIN + 32] * rih;
        biasg[p] = b_ih[g] + b_hh[g];
    }
    f32x4 zero4 = (f32x4){0.f, 0.f, 0.f, 0.f};
#pragma unroll
    for (int p = 0; p < 4; ++p) {
#pragma unroll
        for (int kt = 0; kt < 5; ++kt) asm volatile("" : "+v"(Bf[p][kt]));
        asm volatile("" : "+v"(biasg[p]), "+v"(w32g[p]));
    }
    asm volatile("" : "+v"(zero4));
    const float fcwj = fc_w[jcol] * rfc;
    const float aw0 = attn_w[2 * l];
    const float aw1 = attn_w[2 * l + 1];

    // ================= Phase E: lstm main (R11 structure) =================
    // zero h_{-1} planes (both buffers)
    for (int i = tid; i < 2 * RB * HSP; i += 512) (&hs[0][0][0])[i] = (_Float16)0.f;
    // stage chunk 0 + ss[0] (sentinel spin; producers are ~in lockstep)
    if (tid < 256) {
        const int c4 = tid & 7, rr = (tid >> 3) & 1, k = tid >> 4;
        float4 xv = *reinterpret_cast<const float4*>(x + ((size_t)(b0 + rr) * TT + k) * CC + c4 * 4);
        half4v hv = {(_Float16)xv.x, (_Float16)xv.y, (_Float16)xv.z, (_Float16)xv.w};
        *(half4v*)&xs[0][k][rr][c4 * 4] = hv;
    }
    if (tid < CH) ss[0][tid] = load_s(&ws[tid]);

    float c_st = 0.f, P = 0.f, hprev = 0.f, hpp = 0.f;  // per-lane, row r
    float Sreg = 0.f;                                    // lane 63 of waves 0,1
    __syncthreads();

    for (int tc = 0; tc < NCH; ++tc) {
        const int cb = tc & 1;

        // stage next chunk
        if (tc + 1 < NCH) {
            const int nb  = (tc + 1) & 1;
            const int t0n = (tc + 1) * CH;
            if (tid < 256) {
                const int c4 = tid & 7, rr = (tid >> 3) & 1, k = tid >> 4;
                float4 xv = *reinterpret_cast<const float4*>(
                    x + ((size_t)(b0 + rr) * TT + (t0n + k)) * CC + c4 * 4);
                half4v hv = {(_Float16)xv.x, (_Float16)xv.y, (_Float16)xv.z, (_Float16)xv.w};
                *(half4v*)&xs[nb][k][rr][c4 * 4] = hv;
            }
            if (tid < CH) ss[nb][tid] = load_s(&ws[t0n + tid]);
        }

        for (int k = 0; k < CH; ++k) {
            const int t  = tc * CH + k;
            const int hb = (t + 1) & 1;    // buffer holding h_{t-1}

            // ---- A-frags: all lanes read duplicated rows (m&1) ----
            half8 ah0 = *(const half8*)&hs[hb][m & 1][0 * 32 + q * 8];
            half8 ah1 = *(const half8*)&hs[hb][m & 1][1 * 32 + q * 8];
            half8 ah2 = *(const half8*)&hs[hb][m & 1][2 * 32 + q * 8];
            half8 ah3 = *(const half8*)&hs[hb][m & 1][3 * 32 + q * 8];
            half8 ah4 = *(const half8*)&xs[cb][k][m & 1][q * 8];
            const float s_t = ss[cb][k];

            // logit source read issued early (h_{t-1}, buffer hb)
            float dotp = 0.f;
            if (t > 0 && w < RB) {
                half2v hh = *(const half2v*)&hs[hb][w][2 * l];
                dotp = fmaf(aw0, (float)hh[0], aw1 * (float)hh[1]);
            }

            // ---- P update for h_{t-2} (beta written at step t-1) ----
            if (t >= 2) P = fmaf(bcast[(t - 1) & 1][r], hpp, P);

            // ---- gates: 20 MFMA from zero C, 4 interleaved chains ----
            f32x4 acc0 = MFMA16H(ah0, Bf[0][0], zero4);
            f32x4 acc1 = MFMA16H(ah0, Bf[1][0], zero4);
            f32x4 acc2 = MFMA16H(ah0, Bf[2][0], zero4);
            f32x4 acc3 = MFMA16H(ah0, Bf[3][0], zero4);
            acc0 = MFMA16H(ah1, Bf[0][1], acc0);
            acc1 = MFMA16H(ah1, Bf[1][1], acc1);
            acc2 = MFMA16H(ah1, Bf[2][1], acc2);
            acc3 = MFMA16H(ah1, Bf[3][1], acc3);
            acc0 = MFMA16H(ah2, Bf[0][2], acc0);
            acc1 = MFMA16H(ah2, Bf[1][2], acc1);
            acc2 = MFMA16H(ah2, Bf[2][2], acc2);
            acc3 = MFMA16H(ah2, Bf[3][2], acc3);
            acc0 = MFMA16H(ah3, Bf[0][3], acc0);
            acc1 = MFMA16H(ah3, Bf[1][3], acc1);
            acc2 = MFMA16H(ah3, Bf[2][3], acc2);
            acc3 = MFMA16H(ah3, Bf[3][3], acc3);
            acc0 = MFMA16H(ah4, Bf[0][4], acc0);
            acc1 = MFMA16H(ah4, Bf[1][4], acc1);
            acc2 = MFMA16H(ah4, Bf[2][4], acc2);
            acc3 = MFMA16H(ah4, Bf[3][4], acc3);

            // ---- logit reduction (DPP) overlaps MFMA latency ----
            if (t > 0 && w < RB) {
                float tot = wave_sum_dpp(dotp);
                if (l == 63) {
                    float beta = __expf(tot + attb);
                    Sreg += beta;
                    bcast[t & 1][w] = beta;
                }
            }

            // ---- activations: full wave, reg r = this lane's row ----
            {
                float g0 = acc0[r] + fmaf(w32g[0], s_t, biasg[0]);
                float g1 = acc1[r] + fmaf(w32g[1], s_t, biasg[1]);
                float g2 = acc2[r] + fmaf(w32g[2], s_t, biasg[2]);
                float g3 = acc3[r] + fmaf(w32g[3], s_t, biasg[3]);
                float ig = fsig(g0);
                float fg = fsig(g1);
                float gg = ftanh(g2);
                float og = fsig(g3);
                c_st = fmaf(fg, c_st, ig * gg);
                float hv = og * ftanh(c_st);
                hpp   = hprev;
                hprev = hv;
                if (q < 2) hs[t & 1][r][jcol] = (_Float16)hv;
            }

            __syncthreads();   // single barrier per step
        }
    }

    // ---- epilogue ----
    P = fmaf(bcast[1][r], hpp, P);
    if (w < RB) {
        half2v hh = *(const half2v*)&hs[1][w][2 * l];
        float dotp = fmaf(aw0, (float)hh[0], aw1 * (float)hh[1]);
        float tot = wave_sum_dpp(dotp);
        if (l == 63) {
            float beta = __expf(tot + attb);
            Sreg += beta;
            bcast[0][w] = beta;
            Sf[w] = Sreg;
        }
    }
    __syncthreads();
    {
        float Pv = fmaf(bcast[0][r], hprev, P);
        float v  = Pv * __builtin_amdgcn_rcpf(Sf[r]) * fcwj;
        float rs = row_sum_dpp(v);
        if (l == 15) part[w][0] = rs;       // row 0 sum (q=0)
        if (l == 31) part[w][1] = rs;       // row 1 sum (q=1)
    }
    __syncthreads();
    if (tid < RB) {
        float a = 0.f;
#pragma unroll
        for (int i = 0; i < 8; ++i) a += part[i][tid];
        out[b0 + tid] = a + fc_b[0];
    }
}

// ---------------------------------------------------------------------------
extern "C" void kernel_launch(void* const* d_in, const int* in_sizes, int n_in,
                              void* d_out, int out_size, void* d_ws, size_t ws_size,
                              hipStream_t stream) {
    const float* x      = (const float*)d_in[0];
    const float* w_ih   = (const float*)d_in[1];
    const float* u_ih   = (const float*)d_in[2];
    const float* w_hh   = (const float*)d_in[3];
    const float* u_hh   = (const float*)d_in[4];
    const float* b_ih   = (const float*)d_in[5];
    const float* b_hh   = (const float*)d_in[6];
    const float* attn_w = (const float*)d_in[7];
    const float* attn_b = (const float*)d_in[8];
    const float* fc_w   = (const float*)d_in[9];
    const float* u_fc   = (const float*)d_in[10];
    const float* fc_b   = (const float*)d_in[11];
    float* ws  = (float*)d_ws;
    float* out = (float*)d_out;

    critic_fused<<<BB / RB, 512, 0, stream>>>(x, w_ih, u_ih, w_hh, u_hh, b_ih, b_hh,
                                              attn_w, attn_b, fc_w, u_fc, fc_b, ws, out);
}

// Round 17
// 474.727 us; speedup vs baseline: 1.1204x; 1.0602x over previous
//
#include <hip/hip_runtime.h>
#include <math.h>

#define TT 512
#define BB 512
#define CC 32
#define CIN 33
#define HH 128
#define EPSF 1e-12f
#define CH 16              // timesteps per x-chunk staged in LDS
#define NCH (TT / CH)
#define RB 2               // batch rows per block
#define HSP 160            // hs row stride (halves): 320 B == 16 banks -> rows disjoint
#define XSP 96             // xs row stride (halves): 192 B == 16 banks

typedef _Float16 half8 __attribute__((ext_vector_type(8)));
typedef _Float16 half4v __attribute__((ext_vector_type(4)));
typedef _Float16 half2v __attribute__((ext_vector_type(2)));
typedef float f32x4 __attribute__((ext_vector_type(4)));

#define MFMA16H(a, b, c) __builtin_amdgcn_mfma_f32_16x16x32_f16(a, b, c, 0, 0, 0)

__device__ __forceinline__ float fsig(float x) {
    return __builtin_amdgcn_rcpf(1.f + __expf(-x));
}
__device__ __forceinline__ float ftanh(float x) {
    return 1.f - 2.f * __builtin_amdgcn_rcpf(1.f + __expf(2.f * x));
}
// full-wave (64) sum via DPP; result valid on lane 63 ONLY.
__device__ __forceinline__ float wave_sum_dpp(float x) {
    x += __int_as_float(__builtin_amdgcn_update_dpp(0, __float_as_int(x), 0x111, 0xf, 0xf, true));
    x += __int_as_float(__builtin_amdgcn_update_dpp(0, __float_as_int(x), 0x112, 0xf, 0xf, true));
    x += __int_as_float(__builtin_amdgcn_update_dpp(0, __float_as_int(x), 0x114, 0xf, 0xf, true));
    x += __int_as_float(__builtin_amdgcn_update_dpp(0, __float_as_int(x), 0x118, 0xf, 0xf, true));
    x += __int_as_float(__builtin_amdgcn_update_dpp(0, __float_as_int(x), 0x142, 0xa, 0xf, true));
    x += __int_as_float(__builtin_amdgcn_update_dpp(0, __float_as_int(x), 0x143, 0xc, 0xf, true));
    return x;
}
// sum within each 16-lane row; result valid on lanes 15/31/47/63.
__device__ __forceinline__ float row_sum_dpp(float x) {
    x += __int_as_float(__builtin_amdgcn_update_dpp(0, __float_as_int(x), 0x111, 0xf, 0xf, true));
    x += __int_as_float(__builtin_amdgcn_update_dpp(0, __float_as_int(x), 0x112, 0xf, 0xf, true));
    x += __int_as_float(__builtin_amdgcn_update_dpp(0, __float_as_int(x), 0x114, 0xf, 0xf, true));
    x += __int_as_float(__builtin_amdgcn_update_dpp(0, __float_as_int(x), 0x118, 0xf, 0xf, true));
    return x;
}
// spin-load s[t]: ws is 0xAA-poisoned each launch (sentinel). Relaxed order is
// sufficient: the 4-byte value IS the data; AGENT scope gives cross-XCD
// visibility. No acquire -> no L1 invalidate / vmcnt drain in the hot path.
__device__ __forceinline__ float load_s(const float* p) {
    float v = __hip_atomic_load(p, __ATOMIC_RELAXED, __HIP_MEMORY_SCOPE_AGENT);
    for (int it = 0; it < 100000000 && __float_as_uint(v) == 0xAAAAAAAAu; ++it)
        v = __hip_atomic_load(p, __ATOMIC_RELAXED, __HIP_MEMORY_SCOPE_AGENT);
    return v;
}

// ---------------------------------------------------------------------------
// Fused kernel, NO global barrier. 256 blocks x 512 threads, waves_per_eu(2,2).
// R17: prep phases made latency-tolerant -- sigma loops unrolled with
// independent accumulators (R16's rolled loops paid ~200 cyc L2 latency per
// iteration), phase-A reduction via shfl_xor (6 barriers vs 14), relaxed
// atomics for the s[t] mailbox.
// ---------------------------------------------------------------------------
__global__ __attribute__((amdgpu_flat_work_group_size(512, 512), amdgpu_waves_per_eu(2, 2)))
void critic_fused(
    const float* __restrict__ x,
    const float* __restrict__ w_ih, const float* __restrict__ u_ih,
    const float* __restrict__ w_hh, const float* __restrict__ u_hh,
    const float* __restrict__ b_ih, const float* __restrict__ b_hh,
    const float* __restrict__ attn_w, const float* __restrict__ attn_b,
    const float* __restrict__ fc_w, const float* __restrict__ u_fc,
    const float* __restrict__ fc_b,
    float* __restrict__ ws,
    float* __restrict__ out)
{
    const int tid = threadIdx.x;
    const int w   = tid >> 6;          // wave 0..7
    const int l   = tid & 63;          // lane
    const int m   = l & 15;            // A-row / B-col index
    const int q   = l >> 4;            // quad 0..3
    const int r   = q & 1;             // this lane's batch row (duplicated rows)
    const int b0  = blockIdx.x * RB;
    const int jcol = 16 * w + m;       // this lane's h column

    // ---- LDS ----
    __shared__ float4 sS[8][8];                             // std wave-partials
    __shared__ float4 sQ[8][8];
    __shared__ float red[512];                              // sigma scratch
    __shared__ float vv[128];
    __shared__ float sigS[3];                               // sig_ih, sig_hh, sig_fc
    __shared__ __align__(16) _Float16 hs[2][RB][HSP];       // h planes
    __shared__ __align__(16) _Float16 xs[2][CH][RB][XSP];   // x chunks
    __shared__ float ss[2][CH];
    __shared__ __align__(8) float bcast[2][RB];             // beta per row
    __shared__ float Sf[RB];
    __shared__ float part[8][RB];                           // FC partials

    // ================= Phase A: std for t = 2*bid, 2*bid+1 =================
    {
        const int c4 = tid & 7;       // c = c4*4 .. c4*4+3
        const int bs = tid >> 3;      // 64 groups of 8 batch rows
#pragma unroll
        for (int tt = 0; tt < 2; ++tt) {
            const int t = 2 * blockIdx.x + tt;
            float4 S = make_float4(0.f, 0.f, 0.f, 0.f);
            float4 Q = make_float4(0.f, 0.f, 0.f, 0.f);
#pragma unroll
            for (int i = 0; i < 8; ++i) {
                const int b = bs * 8 + i;
                float4 v = *reinterpret_cast<const float4*>(
                    x + ((size_t)b * TT + t) * CC + c4 * 4);
                S.x += v.x; S.y += v.y; S.z += v.z; S.w += v.w;
                Q.x = fmaf(v.x, v.x, Q.x); Q.y = fmaf(v.y, v.y, Q.y);
                Q.z = fmaf(v.z, v.z, Q.z); Q.w = fmaf(v.w, v.w, Q.w);
            }
            // wave-level xor-reduce over lane bits 3..5 (bs within wave)
#pragma unroll
            for (int off = 8; off <= 32; off <<= 1) {
                S.x += __shfl_xor(S.x, off, 64); S.y += __shfl_xor(S.y, off, 64);
                S.z += __shfl_xor(S.z, off, 64); S.w += __shfl_xor(S.w, off, 64);
                Q.x += __shfl_xor(Q.x, off, 64); Q.y += __shfl_xor(Q.y, off, 64);
                Q.z += __shfl_xor(Q.z, off, 64); Q.w += __shfl_xor(Q.w, off, 64);
            }
            if (l < 8) { sS[w][c4] = S; sQ[w][c4] = Q; }   // lane 0..7: c4 = lane
            __syncthreads();
            if (tid < 8) {
                float4 St = make_float4(0.f, 0.f, 0.f, 0.f);
                float4 Qt = make_float4(0.f, 0.f, 0.f, 0.f);
#pragma unroll
                for (int i = 0; i < 8; ++i) {
                    float4 a = sS[i][tid], b4 = sQ[i][tid];
                    St.x += a.x; St.y += a.y; St.z += a.z; St.w += a.w;
                    Qt.x += b4.x; Qt.y += b4.y; Qt.z += b4.z; Qt.w += b4.w;
                }
                float st = 0.f;
#pragma unroll
                for (int i = 0; i < 4; ++i) {
                    float s1 = (i == 0) ? St.x : (i == 1) ? St.y : (i == 2) ? St.z : St.w;
                    float q1 = (i == 0) ? Qt.x : (i == 1) ? Qt.y : (i == 2) ? Qt.z : Qt.w;
                    float mean = s1 / 512.0f;
                    float var  = (q1 - 512.0f * mean * mean) / 511.0f;
                    st += sqrtf(fmaxf(var, 0.f));
                }
                red[tid] = st;
            }
            __syncthreads();
            if (tid == 0) {
                float mm = 0.f;
#pragma unroll
                for (int i = 0; i < 8; ++i) mm += red[i];
                __hip_atomic_store(&ws[t], mm / 32.0f, __ATOMIC_RELAXED,
                                   __HIP_MEMORY_SCOPE_AGENT);
            }
            __syncthreads();
        }
    }

    // ================= Phase B: block-local sigmas (unrolled) =================
    {
        const int wv_ = w;
        {   // sigma_hh
            const int c = tid & 127, qq = tid >> 7;
            const float* wp = w_hh + (size_t)(qq * 128) * HH + c;
            const float* up = u_hh + qq * 128;
            float a0 = 0.f, a1 = 0.f, a2 = 0.f, a3 = 0.f;
#pragma unroll 4
            for (int g = 0; g < 128; g += 4) {
                a0 = fmaf(wp[(size_t)(g + 0) * HH], up[g + 0], a0);
                a1 = fmaf(wp[(size_t)(g + 1) * HH], up[g + 1], a1);
                a2 = fmaf(wp[(size_t)(g + 2) * HH], up[g + 2], a2);
                a3 = fmaf(wp[(size_t)(g + 3) * HH], up[g + 3], a3);
            }
            red[tid] = (a0 + a1) + (a2 + a3);
            __syncthreads();
            if (tid < 128) vv[tid] = red[tid] + red[tid + 128] + red[tid + 256] + red[tid + 384];
            __syncthreads();
            red[tid] = (tid < 128) ? vv[tid] * vv[tid] : 0.f;
            __syncthreads();
            for (int s = 64; s >= 1; s >>= 1) { if (tid < s) red[tid] += red[tid + s]; __syncthreads(); }
            const float nv = sqrtf(red[0]);
            __syncthreads();
            if (tid < 128) vv[tid] = vv[tid] / (nv + EPSF);
            __syncthreads();
            float sq = 0.f;
            float2 vl = *reinterpret_cast<const float2*>(&vv[2 * l]);
#pragma unroll 4
            for (int gi = 0; gi < 64; ++gi) {
                const int g = wv_ * 64 + gi;
                float2 wl = *reinterpret_cast<const float2*>(&w_hh[(size_t)g * HH + 2 * l]);
                float p  = fmaf(wl.x, vl.x, wl.y * vl.y);
                float tot = wave_sum_dpp(p);
                sq = fmaf(tot, tot, sq);
            }
            if (l == 63) red[wv_] = sq;
            __syncthreads();
            if (tid == 0) {
                float ns2 = 0.f;
                for (int i = 0; i < 8; ++i) ns2 += red[i];
                sigS[1] = ns2 / (sqrtf(ns2) + EPSF);
            }
            __syncthreads();
        }
        {   // sigma_ih : u-projection split across 8 waves
            if (l < CIN) {
                float a0 = 0.f, a1 = 0.f;
#pragma unroll 4
                for (int gi = 0; gi < 64; gi += 2) {
                    const int g = wv_ * 64 + gi;
                    a0 = fmaf(w_ih[(size_t)(g + 0) * CIN + l], u_ih[g + 0], a0);
                    a1 = fmaf(w_ih[(size_t)(g + 1) * CIN + l], u_ih[g + 1], a1);
                }
                red[wv_ * 64 + l] = a0 + a1;
            }
            __syncthreads();
            if (tid < CIN) {
                float v = 0.f;
#pragma unroll
                for (int i = 0; i < 8; ++i) v += red[i * 64 + tid];
                vv[tid] = v;
            }
            __syncthreads();
            if (tid == 0) {
                float n2 = 0.f;
                for (int i = 0; i < CIN; ++i) n2 += vv[i] * vv[i];
                red[400] = sqrtf(n2);
            }
            __syncthreads();
            const float nv = red[400];
            if (tid < CIN) vv[tid] = vv[tid] / (nv + EPSF);
            __syncthreads();
            float vl = (l < CIN) ? vv[l] : 0.f;
            float sq = 0.f;
#pragma unroll 4
            for (int gi = 0; gi < 64; ++gi) {
                const int g = wv_ * 64 + gi;
                float p = (l < CIN) ? w_ih[(size_t)g * CIN + l] * vl : 0.f;
                float tot = wave_sum_dpp(p);
                sq = fmaf(tot, tot, sq);
            }
            if (l == 63) red[wv_] = sq;
            __syncthreads();
            if (tid == 0) {
                float ns2 = 0.f;
                for (int i = 0; i < 8; ++i) ns2 += red[i];
                sigS[0] = ns2 / (sqrtf(ns2) + EPSF);
            }
            __syncthreads();
        }
        {   // sigma_fc
            red[tid] = (tid < 128) ? fc_w[tid] * fc_w[tid] : 0.f;
            __syncthreads();
            for (int s = 64; s >= 1; s >>= 1) { if (tid < s) red[tid] += red[tid + s]; __syncthreads(); }
            if (tid == 0) {
                float nw2 = red[0];
                float u0  = u_fc[0];
                float nv  = fabsf(u0) * sqrtf(nw2);
                float wv  = u0 * nw2 / (nv + EPSF);
                sigS[2]   = wv * wv / (fabsf(wv) + EPSF);
            }
            __syncthreads();
        }
    }
    const float rih = 1.f / sigS[0];
    const float rhh = 1.f / sigS[1];
    const float rfc = 1.f / sigS[2];
    const float attb = attn_b[0];

    // ================= Phase C: weight conversion (R11) =================
    half8 Bf[4][5];
    float biasg[4], w32g[4];
#pragma unroll
    for (int p = 0; p < 4; ++p) {
        const int g = 16 * w + 128 * p + m;
#pragma unroll
        for (int kt = 0; kt < 4; ++kt) {
            const float* src = w_hh + (size_t)g * HH + kt * 32 + q * 8;
#pragma unroll
            for (int i = 0; i < 8; ++i) Bf[p][kt][i] = (_Float16)(src[i] * rhh);
        }
        {
            const float* src = w_ih + (size_t)g * CIN + q * 8;
#pragma unroll
            for (int i = 0; i < 8; ++i) Bf[p][4][i] = (_Float16)(src[i] * rih);
        }
        w32g[p]  = w_ih[(size_t)g * CIN + 32] * rih;
        biasg[p] = b_ih[g] + b_hh[g];
    }
    f32x4 zero4 = (f32x4){0.f, 0.f, 0.f, 0.f};
#pragma unroll
    for (int p = 0; p < 4; ++p) {
#pragma unroll
        for (int kt = 0; kt < 5; ++kt) asm volatile("" : "+v"(Bf[p][kt]));
        asm volatile("" : "+v"(biasg[p]), "+v"(w32g[p]));
    }
    asm volatile("" : "+v"(zero4));
    const float fcwj = fc_w[jcol] * rfc;
    const float aw0 = attn_w[2 * l];
    const float aw1 = attn_w[2 * l + 1];

    // ================= Phase E: lstm main (R11 structure) =================
    // zero h_{-1} planes (both buffers)
    for (int i = tid; i < 2 * RB * HSP; i += 512) (&hs[0][0][0])[i] = (_Float16)0.f;
    // stage chunk 0 + ss[0] (sentinel spin; producers are ~in lockstep)
    if (tid < 256) {
        const int c4 = tid & 7, rr = (tid >> 3) & 1, k = tid >> 4;
        float4 xv = *reinterpret_cast<const float4*>(x + ((size_t)(b0 + rr) * TT + k) * CC + c4 * 4);
        half4v hv = {(_Float16)xv.x, (_Float16)xv.y, (_Float16)xv.z, (_Float16)xv.w};
        *(half4v*)&xs[0][k][rr][c4 * 4] = hv;
    }
    if (tid < CH) ss[0][tid] = load_s(&ws[tid]);

    float c_st = 0.f, P = 0.f, hprev = 0.f, hpp = 0.f;  // per-lane, row r
    float Sreg = 0.f;                                    // lane 63 of waves 0,1
    __syncthreads();

    for (int tc = 0; tc < NCH; ++tc) {
        const int cb = tc & 1;

        // stage next chunk
        if (tc + 1 < NCH) {
            const int nb  = (tc + 1) & 1;
            const int t0n = (tc + 1) * CH;
            if (tid < 256) {
                const int c4 = tid & 7, rr = (tid >> 3) & 1, k = tid >> 4;
                float4 xv = *reinterpret_cast<const float4*>(
                    x + ((size_t)(b0 + rr) * TT + (t0n + k)) * CC + c4 * 4);
                half4v hv = {(_Float16)xv.x, (_Float16)xv.y, (_Float16)xv.z, (_Float16)xv.w};
                *(half4v*)&xs[nb][k][rr][c4 * 4] = hv;
            }
            if (tid < CH) ss[nb][tid] = load_s(&ws[t0n + tid]);
        }

        for (int k = 0; k < CH; ++k) {
            const int t  = tc * CH + k;
            const int hb = (t + 1) & 1;    // buffer holding h_{t-1}

            // ---- A-frags: all lanes read duplicated rows (m&1) ----
            half8 ah0 = *(const half8*)&hs[hb][m & 1][0 * 32 + q * 8];
            half8 ah1 = *(const half8*)&hs[hb][m & 1][1 * 32 + q * 8];
            half8 ah2 = *(const half8*)&hs[hb][m & 1][2 * 32 + q * 8];
            half8 ah3 = *(const half8*)&hs[hb][m & 1][3 * 32 + q * 8];
            half8 ah4 = *(const half8*)&xs[cb][k][m & 1][q * 8];
            const float s_t = ss[cb][k];

            // logit source read issued early (h_{t-1}, buffer hb)
            float dotp = 0.f;
            if (t > 0 && w < RB) {
                half2v hh = *(const half2v*)&hs[hb][w][2 * l];
                dotp = fmaf(aw0, (float)hh[0], aw1 * (float)hh[1]);
            }

            // ---- P update for h_{t-2} (beta written at step t-1) ----
            if (t >= 2) P = fmaf(bcast[(t - 1) & 1][r], hpp, P);

            // ---- gates: 20 MFMA from zero C, 4 interleaved chains ----
            f32x4 acc0 = MFMA16H(ah0, Bf[0][0], zero4);
            f32x4 acc1 = MFMA16H(ah0, Bf[1][0], zero4);
            f32x4 acc2 = MFMA16H(ah0, Bf[2][0], zero4);
            f32x4 acc3 = MFMA16H(ah0, Bf[3][0], zero4);
            acc0 = MFMA16H(ah1, Bf[0][1], acc0);
            acc1 = MFMA16H(ah1, Bf[1][1], acc1);
            acc2 = MFMA16H(ah1, Bf[2][1], acc2);
            acc3 = MFMA16H(ah1, Bf[3][1], acc3);
            acc0 = MFMA16H(ah2, Bf[0][2], acc0);
            acc1 = MFMA16H(ah2, Bf[1][2], acc1);
            acc2 = MFMA16H(ah2, Bf[2][2], acc2);
            acc3 = MFMA16H(ah2, Bf[3][2], acc3);
            acc0 = MFMA16H(ah3, Bf[0][3], acc0);
            acc1 = MFMA16H(ah3, Bf[1][3], acc1);
            acc2 = MFMA16H(ah3, Bf[2][3], acc2);
            acc3 = MFMA16H(ah3, Bf[3][3], acc3);
            acc0 = MFMA16H(ah4, Bf[0][4], acc0);
            acc1 = MFMA16H(ah4, Bf[1][4], acc1);
            acc2 = MFMA16H(ah4, Bf[2][4], acc2);
            acc3 = MFMA16H(ah4, Bf[3][4], acc3);

            // ---- logit reduction (DPP) overlaps MFMA latency ----
            if (t > 0 && w < RB) {
                float tot = wave_sum_dpp(dotp);
                if (l == 63) {
                    float beta = __expf(tot + attb);
                    Sreg += beta;
                    bcast[t & 1][w] = beta;
                }
            }

            // ---- activations: full wave, reg r = this lane's row ----
            {
                float g0 = acc0[r] + fmaf(w32g[0], s_t, biasg[0]);
                float g1 = acc1[r] + fmaf(w32g[1], s_t, biasg[1]);
                float g2 = acc2[r] + fmaf(w32g[2], s_t, biasg[2]);
                float g3 = acc3[r] + fmaf(w32g[3], s_t, biasg[3]);
                float ig = fsig(g0);
                float fg = fsig(g1);
                float gg = ftanh(g2);
                float og = fsig(g3);
                c_st = fmaf(fg, c_st, ig * gg);
                float hv = og * ftanh(c_st);
                hpp   = hprev;
                hprev = hv;
                if (q < 2) hs[t & 1][r][jcol] = (_Float16)hv;
            }

            __syncthreads();   // single barrier per step
        }
    }

    // ---- epilogue ----
    P = fmaf(bcast[1][r], hpp, P);
    if (w < RB) {
        half2v hh = *(const half2v*)&hs[1][w][2 * l];
        float dotp = fmaf(aw0, (float)hh[0], aw1 * (float)hh[1]);
        float tot = wave_sum_dpp(dotp);
        if (l == 63) {
            float beta = __expf(tot + attb);
            Sreg += beta;
            bcast[0][w] = beta;
            Sf[w] = Sreg;
        }
    }
    __syncthreads();
    {
        float Pv = fmaf(bcast[0][r], hprev, P);
        float v  = Pv * __builtin_amdgcn_rcpf(Sf[r]) * fcwj;
        float rs = row_sum_dpp(v);
        if (l == 15) part[w][0] = rs;       // row 0 sum (q=0)
        if (l == 31) part[w][1] = rs;       // row 1 sum (q=1)
    }
    __syncthreads();
    if (tid < RB) {
        float a = 0.f;
#pragma unroll
        for (int i = 0; i < 8; ++i) a += part[i][tid];
        out[b0 + tid] = a + fc_b[0];
    }
}

// ---------------------------------------------------------------------------
extern "C" void kernel_launch(void* const* d_in, const int* in_sizes, int n_in,
                              void* d_out, int out_size, void* d_ws, size_t ws_size,
                              hipStream_t stream) {
    const float* x      = (const float*)d_in[0];
    const float* w_ih   = (const float*)d_in[1];
    const float* u_ih   = (const float*)d_in[2];
    const float* w_hh   = (const float*)d_in[3];
    const float* u_hh   = (const float*)d_in[4];
    const float* b_ih   = (const float*)d_in[5];
    const float* b_hh   = (const float*)d_in[6];
    const float* attn_w = (const float*)d_in[7];
    const float* attn_b = (const float*)d_in[8];
    const float* fc_w   = (const float*)d_in[9];
    const float* u_fc   = (const float*)d_in[10];
    const float* fc_b   = (const float*)d_in[11];
    float* ws  = (float*)d_ws;
    float* out = (float*)d_out;

    critic_fused<<<BB / RB, 512, 0, stream>>>(x, w_ih, u_ih, w_hh, u_hh, b_ih, b_hh,
                                              attn_w, attn_b, fc_w, u_fc, fc_b, ws, out);
}

// Round 18
// 467.973 us; speedup vs baseline: 1.1366x; 1.0144x over previous
//
#include <hip/hip_runtime.h>
#include <math.h>

#define TT 512
#define BB 512
#define CC 32
#define CIN 33
#define HH 128
#define EPSF 1e-12f
#define CH 16              // timesteps per x-chunk staged in LDS
#define NCH (TT / CH)
#define RB 2               // batch rows per block
#define HSP 160            // hs row stride (halves): 320 B == 16 banks -> rows disjoint
#define XSP 96             // xs row stride (halves): 192 B == 16 banks

typedef _Float16 half8 __attribute__((ext_vector_type(8)));
typedef _Float16 half4v __attribute__((ext_vector_type(4)));
typedef _Float16 half2v __attribute__((ext_vector_type(2)));
typedef float f32x4 __attribute__((ext_vector_type(4)));

#define MFMA16H(a, b, c) __builtin_amdgcn_mfma_f32_16x16x32_f16(a, b, c, 0, 0, 0)

__device__ __forceinline__ float fsig(float x) {
    return __builtin_amdgcn_rcpf(1.f + __expf(-x));
}
__device__ __forceinline__ float ftanh(float x) {
    return 1.f - 2.f * __builtin_amdgcn_rcpf(1.f + __expf(2.f * x));
}
// full-wave (64) sum via DPP; result valid on lane 63 ONLY.
__device__ __forceinline__ float wave_sum_dpp(float x) {
    x += __int_as_float(__builtin_amdgcn_update_dpp(0, __float_as_int(x), 0x111, 0xf, 0xf, true));
    x += __int_as_float(__builtin_amdgcn_update_dpp(0, __float_as_int(x), 0x112, 0xf, 0xf, true));
    x += __int_as_float(__builtin_amdgcn_update_dpp(0, __float_as_int(x), 0x114, 0xf, 0xf, true));
    x += __int_as_float(__builtin_amdgcn_update_dpp(0, __float_as_int(x), 0x118, 0xf, 0xf, true));
    x += __int_as_float(__builtin_amdgcn_update_dpp(0, __float_as_int(x), 0x142, 0xa, 0xf, true));
    x += __int_as_float(__builtin_amdgcn_update_dpp(0, __float_as_int(x), 0x143, 0xc, 0xf, true));
    return x;
}
// sum within each 16-lane row; result valid on lanes 15/31/47/63.
__device__ __forceinline__ float row_sum_dpp(float x) {
    x += __int_as_float(__builtin_amdgcn_update_dpp(0, __float_as_int(x), 0x111, 0xf, 0xf, true));
    x += __int_as_float(__builtin_amdgcn_update_dpp(0, __float_as_int(x), 0x112, 0xf, 0xf, true));
    x += __int_as_float(__builtin_amdgcn_update_dpp(0, __float_as_int(x), 0x114, 0xf, 0xf, true));
    x += __int_as_float(__builtin_amdgcn_update_dpp(0, __float_as_int(x), 0x118, 0xf, 0xf, true));
    return x;
}
// spin-load s[t]: ws is 0xAA-poisoned each launch (sentinel). Relaxed order is
// sufficient: the 4-byte value IS the data; AGENT scope gives cross-XCD
// visibility.
__device__ __forceinline__ float load_s(const float* p) {
    float v = __hip_atomic_load(p, __ATOMIC_RELAXED, __HIP_MEMORY_SCOPE_AGENT);
    for (int it = 0; it < 100000000 && __float_as_uint(v) == 0xAAAAAAAAu; ++it)
        v = __hip_atomic_load(p, __ATOMIC_RELAXED, __HIP_MEMORY_SCOPE_AGENT);
    return v;
}

// ---------------------------------------------------------------------------
// Fused kernel, NO global barrier. 256 blocks x 512 threads, waves_per_eu(2,2).
// R18: prep software-pipelined -- phase-A x loads (HBM, ~900cyc) are issued
// into registers FIRST, sigma_hh's L2-bound projection runs in their shadow,
// then the std reduction consumes the registers. Both timesteps' reductions
// merged into one barrier region; std combine overlaps vv-reduction via
// disjoint thread groups.
// ---------------------------------------------------------------------------
__global__ __attribute__((amdgpu_flat_work_group_size(512, 512), amdgpu_waves_per_eu(2, 2)))
void critic_fused(
    const float* __restrict__ x,
    const float* __restrict__ w_ih, const float* __restrict__ u_ih,
    const float* __restrict__ w_hh, const float* __restrict__ u_hh,
    const float* __restrict__ b_ih, const float* __restrict__ b_hh,
    const float* __restrict__ attn_w, const float* __restrict__ attn_b,
    const float* __restrict__ fc_w, const float* __restrict__ u_fc,
    const float* __restrict__ fc_b,
    float* __restrict__ ws,
    float* __restrict__ out)
{
    const int tid = threadIdx.x;
    const int w   = tid >> 6;          // wave 0..7
    const int l   = tid & 63;          // lane
    const int m   = l & 15;            // A-row / B-col index
    const int q   = l >> 4;            // quad 0..3
    const int r   = q & 1;             // this lane's batch row (duplicated rows)
    const int b0  = blockIdx.x * RB;
    const int jcol = 16 * w + m;       // this lane's h column

    // ---- LDS ----
    __shared__ float4 sSS[2][8][8];                         // std wave-partials per tt
    __shared__ float4 sQQ[2][8][8];
    __shared__ float stdp[2][8];                            // per-c4 std partials
    __shared__ float red[512];                              // sigma scratch
    __shared__ float vv[128];
    __shared__ float sigS[3];                               // sig_ih, sig_hh, sig_fc
    __shared__ __align__(16) _Float16 hs[2][RB][HSP];       // h planes
    __shared__ __align__(16) _Float16 xs[2][CH][RB][XSP];   // x chunks
    __shared__ float ss[2][CH];
    __shared__ __align__(8) float bcast[2][RB];             // beta per row
    __shared__ float Sf[RB];
    __shared__ float part[8][RB];                           // FC partials

    // ===== Phase A loads issued FIRST (HBM latency hidden by phase B) =====
    const int c4 = tid & 7;       // c = c4*4 .. c4*4+3
    const int bs = tid >> 3;      // 64 groups of 8 batch rows
    float4 xa[2][8];
#pragma unroll
    for (int tt = 0; tt < 2; ++tt) {
        const int t = 2 * blockIdx.x + tt;
#pragma unroll
        for (int i = 0; i < 8; ++i)
            xa[tt][i] = *reinterpret_cast<const float4*>(
                x + ((size_t)(bs * 8 + i) * TT + t) * CC + c4 * 4);
    }

    // ===== sigma_hh projection in the loads' shadow (L2-bound) =====
    {
        const int c = tid & 127, qq = tid >> 7;
        const float* wp = w_hh + (size_t)(qq * 128) * HH + c;
        const float* up = u_hh + qq * 128;
        float a0 = 0.f, a1 = 0.f, a2 = 0.f, a3 = 0.f;
#pragma unroll 4
        for (int g = 0; g < 128; g += 4) {
            a0 = fmaf(wp[(size_t)(g + 0) * HH], up[g + 0], a0);
            a1 = fmaf(wp[(size_t)(g + 1) * HH], up[g + 1], a1);
            a2 = fmaf(wp[(size_t)(g + 2) * HH], up[g + 2], a2);
            a3 = fmaf(wp[(size_t)(g + 3) * HH], up[g + 3], a3);
        }
        red[tid] = (a0 + a1) + (a2 + a3);
    }

    // ===== Phase A reduction (registers already landed) =====
#pragma unroll
    for (int tt = 0; tt < 2; ++tt) {
        float4 S = make_float4(0.f, 0.f, 0.f, 0.f);
        float4 Q = make_float4(0.f, 0.f, 0.f, 0.f);
#pragma unroll
        for (int i = 0; i < 8; ++i) {
            float4 v = xa[tt][i];
            S.x += v.x; S.y += v.y; S.z += v.z; S.w += v.w;
            Q.x = fmaf(v.x, v.x, Q.x); Q.y = fmaf(v.y, v.y, Q.y);
            Q.z = fmaf(v.z, v.z, Q.z); Q.w = fmaf(v.w, v.w, Q.w);
        }
#pragma unroll
        for (int off = 8; off <= 32; off <<= 1) {
            S.x += __shfl_xor(S.x, off, 64); S.y += __shfl_xor(S.y, off, 64);
            S.z += __shfl_xor(S.z, off, 64); S.w += __shfl_xor(S.w, off, 64);
            Q.x += __shfl_xor(Q.x, off, 64); Q.y += __shfl_xor(Q.y, off, 64);
            Q.z += __shfl_xor(Q.z, off, 64); Q.w += __shfl_xor(Q.w, off, 64);
        }
        if (l < 8) { sSS[tt][w][c4] = S; sQQ[tt][w][c4] = Q; }
    }
    __syncthreads();   // publishes red[] (projection) + sSS/sQQ

    // disjoint groups: tid<128 -> vv combine; tid 384..399 -> std combine
    if (tid < 128) vv[tid] = red[tid] + red[tid + 128] + red[tid + 256] + red[tid + 384];
    if (tid >= 384 && tid < 400) {
        const int tt2 = (tid - 384) >> 3, cc = (tid - 384) & 7;
        float4 St = make_float4(0.f, 0.f, 0.f, 0.f);
        float4 Qt = make_float4(0.f, 0.f, 0.f, 0.f);
#pragma unroll
        for (int i = 0; i < 8; ++i) {
            float4 a = sSS[tt2][i][cc], b4 = sQQ[tt2][i][cc];
            St.x += a.x; St.y += a.y; St.z += a.z; St.w += a.w;
            Qt.x += b4.x; Qt.y += b4.y; Qt.z += b4.z; Qt.w += b4.w;
        }
        float st = 0.f;
#pragma unroll
        for (int i = 0; i < 4; ++i) {
            float s1 = (i == 0) ? St.x : (i == 1) ? St.y : (i == 2) ? St.z : St.w;
            float q1 = (i == 0) ? Qt.x : (i == 1) ? Qt.y : (i == 2) ? Qt.z : Qt.w;
            float mean = s1 / 512.0f;
            float var  = (q1 - 512.0f * mean * mean) / 511.0f;
            st += sqrtf(fmaxf(var, 0.f));
        }
        stdp[tt2][cc] = st;
    }
    __syncthreads();
    // tid 408/409: publish ws[t]; tid<512: square vv for norm reduction
    if (tid >= 408 && tid < 410) {
        const int tt2 = tid - 408;
        float mm = 0.f;
#pragma unroll
        for (int i = 0; i < 8; ++i) mm += stdp[tt2][i];
        __hip_atomic_store(&ws[2 * blockIdx.x + tt2], mm / 32.0f, __ATOMIC_RELAXED,
                           __HIP_MEMORY_SCOPE_AGENT);
    }
    red[tid] = (tid < 128) ? vv[tid] * vv[tid] : 0.f;
    __syncthreads();

    // ===== sigma_hh: norm + W@v =====
    {
        for (int s = 64; s >= 1; s >>= 1) { if (tid < s) red[tid] += red[tid + s]; __syncthreads(); }
        const float nv = sqrtf(red[0]);
        __syncthreads();
        if (tid < 128) vv[tid] = vv[tid] / (nv + EPSF);
        __syncthreads();
        float sq = 0.f;
        float2 vl = *reinterpret_cast<const float2*>(&vv[2 * l]);
#pragma unroll 4
        for (int gi = 0; gi < 64; ++gi) {
            const int g = w * 64 + gi;
            float2 wl = *reinterpret_cast<const float2*>(&w_hh[(size_t)g * HH + 2 * l]);
            float p  = fmaf(wl.x, vl.x, wl.y * vl.y);
            float tot = wave_sum_dpp(p);
            sq = fmaf(tot, tot, sq);
        }
        if (l == 63) red[w] = sq;
        __syncthreads();
        if (tid == 0) {
            float ns2 = 0.f;
            for (int i = 0; i < 8; ++i) ns2 += red[i];
            sigS[1] = ns2 / (sqrtf(ns2) + EPSF);
        }
        __syncthreads();
    }
    // ===== sigma_ih =====
    {
        if (l < CIN) {
            float a0 = 0.f, a1 = 0.f;
#pragma unroll 4
            for (int gi = 0; gi < 64; gi += 2) {
                const int g = w * 64 + gi;
                a0 = fmaf(w_ih[(size_t)(g + 0) * CIN + l], u_ih[g + 0], a0);
                a1 = fmaf(w_ih[(size_t)(g + 1) * CIN + l], u_ih[g + 1], a1);
            }
            red[w * 64 + l] = a0 + a1;
        }
        __syncthreads();
        if (tid < CIN) {
            float v = 0.f;
#pragma unroll
            for (int i = 0; i < 8; ++i) v += red[i * 64 + tid];
            vv[tid] = v;
        }
        __syncthreads();
        if (tid == 0) {
            float n2 = 0.f;
            for (int i = 0; i < CIN; ++i) n2 += vv[i] * vv[i];
            red[400] = sqrtf(n2);
        }
        __syncthreads();
        const float nv = red[400];
        if (tid < CIN) vv[tid] = vv[tid] / (nv + EPSF);
        __syncthreads();
        float vl = (l < CIN) ? vv[l] : 0.f;
        float sq = 0.f;
#pragma unroll 4
        for (int gi = 0; gi < 64; ++gi) {
            const int g = w * 64 + gi;
            float p = (l < CIN) ? w_ih[(size_t)g * CIN + l] * vl : 0.f;
            float tot = wave_sum_dpp(p);
            sq = fmaf(tot, tot, sq);
        }
        if (l == 63) red[w] = sq;
        __syncthreads();
        if (tid == 0) {
            float ns2 = 0.f;
            for (int i = 0; i < 8; ++i) ns2 += red[i];
            sigS[0] = ns2 / (sqrtf(ns2) + EPSF);
        }
        __syncthreads();
    }
    // ===== sigma_fc =====
    {
        red[tid] = (tid < 128) ? fc_w[tid] * fc_w[tid] : 0.f;
        __syncthreads();
        for (int s = 64; s >= 1; s >>= 1) { if (tid < s) red[tid] += red[tid + s]; __syncthreads(); }
        if (tid == 0) {
            float nw2 = red[0];
            float u0  = u_fc[0];
            float nv  = fabsf(u0) * sqrtf(nw2);
            float wv  = u0 * nw2 / (nv + EPSF);
            sigS[2]   = wv * wv / (fabsf(wv) + EPSF);
        }
        __syncthreads();
    }
    const float rih = 1.f / sigS[0];
    const float rhh = 1.f / sigS[1];
    const float rfc = 1.f / sigS[2];
    const float attb = attn_b[0];

    // ================= Phase C: weight conversion (R11) =================
    half8 Bf[4][5];
    float biasg[4], w32g[4];
#pragma unroll
    for (int p = 0; p < 4; ++p) {
        const int g = 16 * w + 128 * p + m;
#pragma unroll
        for (int kt = 0; kt < 4; ++kt) {
            const float* src = w_hh + (size_t)g * HH + kt * 32 + q * 8;
#pragma unroll
            for (int i = 0; i < 8; ++i) Bf[p][kt][i] = (_Float16)(src[i] * rhh);
        }
        {
            const float* src = w_ih + (size_t)g * CIN + q * 8;
#pragma unroll
            for (int i = 0; i < 8; ++i) Bf[p][4][i] = (_Float16)(src[i] * rih);
        }
        w32g[p]  = w_ih[(size_t)g * CIN + 32] * rih;
        biasg[p] = b_ih[g] + b_hh[g];
    }
    f32x4 zero4 = (f32x4){0.f, 0.f, 0.f, 0.f};
#pragma unroll
    for (int p = 0; p < 4; ++p) {
#pragma unroll
        for (int kt = 0; kt < 5; ++kt) asm volatile("" : "+v"(Bf[p][kt]));
        asm volatile("" : "+v"(biasg[p]), "+v"(w32g[p]));
    }
    asm volatile("" : "+v"(zero4));
    const float fcwj = fc_w[jcol] * rfc;
    const float aw0 = attn_w[2 * l];
    const float aw1 = attn_w[2 * l + 1];

    // ================= Phase E: lstm main (R11 structure) =================
    for (int i = tid; i < 2 * RB * HSP; i += 512) (&hs[0][0][0])[i] = (_Float16)0.f;
    if (tid < 256) {
        const int cc4 = tid & 7, rr = (tid >> 3) & 1, k = tid >> 4;
        float4 xv = *reinterpret_cast<const float4*>(x + ((size_t)(b0 + rr) * TT + k) * CC + cc4 * 4);
        half4v hv = {(_Float16)xv.x, (_Float16)xv.y, (_Float16)xv.z, (_Float16)xv.w};
        *(half4v*)&xs[0][k][rr][cc4 * 4] = hv;
    }
    if (tid < CH) ss[0][tid] = load_s(&ws[tid]);

    float c_st = 0.f, P = 0.f, hprev = 0.f, hpp = 0.f;  // per-lane, row r
    float Sreg = 0.f;                                    // lane 63 of waves 0,1
    __syncthreads();

    for (int tc = 0; tc < NCH; ++tc) {
        const int cb = tc & 1;

        // stage next chunk
        if (tc + 1 < NCH) {
            const int nb  = (tc + 1) & 1;
            const int t0n = (tc + 1) * CH;
            if (tid < 256) {
                const int cc4 = tid & 7, rr = (tid >> 3) & 1, k = tid >> 4;
                float4 xv = *reinterpret_cast<const float4*>(
                    x + ((size_t)(b0 + rr) * TT + (t0n + k)) * CC + cc4 * 4);
                half4v hv = {(_Float16)xv.x, (_Float16)xv.y, (_Float16)xv.z, (_Float16)xv.w};
                *(half4v*)&xs[nb][k][rr][cc4 * 4] = hv;
            }
            if (tid < CH) ss[nb][tid] = load_s(&ws[t0n + tid]);
        }

        for (int k = 0; k < CH; ++k) {
            const int t  = tc * CH + k;
            const int hb = (t + 1) & 1;    // buffer holding h_{t-1}

            // ---- A-frags: all lanes read duplicated rows (m&1) ----
            half8 ah0 = *(const half8*)&hs[hb][m & 1][0 * 32 + q * 8];
            half8 ah1 = *(const half8*)&hs[hb][m & 1][1 * 32 + q * 8];
            half8 ah2 = *(const half8*)&hs[hb][m & 1][2 * 32 + q * 8];
            half8 ah3 = *(const half8*)&hs[hb][m & 1][3 * 32 + q * 8];
            half8 ah4 = *(const half8*)&xs[cb][k][m & 1][q * 8];
            const float s_t = ss[cb][k];

            // logit source read issued early (h_{t-1}, buffer hb)
            float dotp = 0.f;
            if (t > 0 && w < RB) {
                half2v hh = *(const half2v*)&hs[hb][w][2 * l];
                dotp = fmaf(aw0, (float)hh[0], aw1 * (float)hh[1]);
            }

            // ---- P update for h_{t-2} (beta written at step t-1) ----
            if (t >= 2) P = fmaf(bcast[(t - 1) & 1][r], hpp, P);

            // ---- gates: 20 MFMA from zero C, 4 interleaved chains ----
            f32x4 acc0 = MFMA16H(ah0, Bf[0][0], zero4);
            f32x4 acc1 = MFMA16H(ah0, Bf[1][0], zero4);
            f32x4 acc2 = MFMA16H(ah0, Bf[2][0], zero4);
            f32x4 acc3 = MFMA16H(ah0, Bf[3][0], zero4);
            acc0 = MFMA16H(ah1, Bf[0][1], acc0);
            acc1 = MFMA16H(ah1, Bf[1][1], acc1);
            acc2 = MFMA16H(ah1, Bf[2][1], acc2);
            acc3 = MFMA16H(ah1, Bf[3][1], acc3);
            acc0 = MFMA16H(ah2, Bf[0][2], acc0);
            acc1 = MFMA16H(ah2, Bf[1][2], acc1);
            acc2 = MFMA16H(ah2, Bf[2][2], acc2);
            acc3 = MFMA16H(ah2, Bf[3][2], acc3);
            acc0 = MFMA16H(ah3, Bf[0][3], acc0);
            acc1 = MFMA16H(ah3, Bf[1][3], acc1);
            acc2 = MFMA16H(ah3, Bf[2][3], acc2);
            acc3 = MFMA16H(ah3, Bf[3][3], acc3);
            acc0 = MFMA16H(ah4, Bf[0][4], acc0);
            acc1 = MFMA16H(ah4, Bf[1][4], acc1);
            acc2 = MFMA16H(ah4, Bf[2][4], acc2);
            acc3 = MFMA16H(ah4, Bf[3][4], acc3);

            // ---- logit reduction (DPP) overlaps MFMA latency ----
            if (t > 0 && w < RB) {
                float tot = wave_sum_dpp(dotp);
                if (l == 63) {
                    float beta = __expf(tot + attb);
                    Sreg += beta;
                    bcast[t & 1][w] = beta;
                }
            }

            // ---- activations: full wave, reg r = this lane's row ----
            {
                float g0 = acc0[r] + fmaf(w32g[0], s_t, biasg[0]);
                float g1 = acc1[r] + fmaf(w32g[1], s_t, biasg[1]);
                float g2 = acc2[r] + fmaf(w32g[2], s_t, biasg[2]);
                float g3 = acc3[r] + fmaf(w32g[3], s_t, biasg[3]);
                float ig = fsig(g0);
                float fg = fsig(g1);
                float gg = ftanh(g2);
                float og = fsig(g3);
                c_st = fmaf(fg, c_st, ig * gg);
                float hv = og * ftanh(c_st);
                hpp   = hprev;
                hprev = hv;
                if (q < 2) hs[t & 1][r][jcol] = (_Float16)hv;
            }

            __syncthreads();   // single barrier per step
        }
    }

    // ---- epilogue ----
    P = fmaf(bcast[1][r], hpp, P);
    if (w < RB) {
        half2v hh = *(const half2v*)&hs[1][w][2 * l];
        float dotp = fmaf(aw0, (float)hh[0], aw1 * (float)hh[1]);
        float tot = wave_sum_dpp(dotp);
        if (l == 63) {
            float beta = __expf(tot + attb);
            Sreg += beta;
            bcast[0][w] = beta;
            Sf[w] = Sreg;
        }
    }
    __syncthreads();
    {
        float Pv = fmaf(bcast[0][r], hprev, P);
        float v  = Pv * __builtin_amdgcn_rcpf(Sf[r]) * fcwj;
        float rs = row_sum_dpp(v);
        if (l == 15) part[w][0] = rs;       // row 0 sum (q=0)
        if (l == 31) part[w][1] = rs;       // row 1 sum (q=1)
    }
    __syncthreads();
    if (tid < RB) {
        float a = 0.f;
#pragma unroll
        for (int i = 0; i < 8; ++i) a += part[i][tid];
        out[b0 + tid] = a + fc_b[0];
    }
}

// ---------------------------------------------------------------------------
extern "C" void kernel_launch(void* const* d_in, const int* in_sizes, int n_in,
                              void* d_out, int out_size, void* d_ws, size_t ws_size,
                              hipStream_t stream) {
    const float* x      = (const float*)d_in[0];
    const float* w_ih   = (const float*)d_in[1];
    const float* u_ih   = (const float*)d_in[2];
    const float* w_hh   = (const float*)d_in[3];
    const float* u_hh   = (const float*)d_in[4];
    const float* b_ih   = (const float*)d_in[5];
    const float* b_hh   = (const float*)d_in[6];
    const float* attn_w = (const float*)d_in[7];
    const float* attn_b = (const float*)d_in[8];
    const float* fc_w   = (const float*)d_in[9];
    const float* u_fc   = (const float*)d_in[10];
    const float* fc_b   = (const float*)d_in[11];
    float* ws  = (float*)d_ws;
    float* out = (float*)d_out;

    critic_fused<<<BB / RB, 512, 0, stream>>>(x, w_ih, u_ih, w_hh, u_hh, b_ih, b_hh,
                                              attn_w, attn_b, fc_w, u_fc, fc_b, ws, out);
}